// Round 10
// baseline (140.218 us; speedup 1.0000x reference)
//
#include <hip/hip_runtime.h>
#include <hip/hip_bf16.h>
#include <math.h>

#define BROWS 4096
#define DIM   512
#define YEMB_E 2097152   // 4096*512, element offset of emb rows in Y
#define TSTRIDE 127      // tile stride (tiles are 128 wide, overlap by 1)
#define NT 33            // tiles per dim; triangle blocks = 33*34/2 = 561

typedef float f32x4 __attribute__((ext_vector_type(4)));
typedef __bf16 bf16x8 __attribute__((ext_vector_type(8)));

// ---------------------------------------------------------------------------
// prep3: wave-per-row, no barriers. 8192 rows (low then emb), 4 rows/block.
// ---------------------------------------------------------------------------
__global__ __launch_bounds__(256) void prep3_kernel(
    const float* __restrict__ low, const float* __restrict__ emb,
    __hip_bfloat16* __restrict__ Y,
    float* __restrict__ s_l, float* __restrict__ r_l,
    float* __restrict__ s_e, float* __restrict__ r_e,
    float* __restrict__ out) {
  const int tid = threadIdx.x;
  const int lane = tid & 63, wid = tid >> 6;
  const int rid = blockIdx.x * 4 + wid;          // 0..8191
  if (blockIdx.x == 0 && tid == 0) out[0] = 0.f;

  const bool is_low = (rid < BROWS);
  const int row = is_low ? rid : rid - BROWS;
  const float* x = (is_low ? low : emb) + (size_t)row * DIM;

  const float4 v0 = ((const float4*)x)[lane * 2];
  const float4 v1 = ((const float4*)x)[lane * 2 + 1];

  float ss = v0.x * v0.x + v0.y * v0.y + v0.z * v0.z + v0.w * v0.w +
             v1.x * v1.x + v1.y * v1.y + v1.z * v1.z + v1.w * v1.w;
#pragma unroll
  for (int o = 1; o < 64; o <<= 1) ss += __shfl_xor(ss, o, 64);
  const float inv = 1.0f / fmaxf(sqrtf(ss), 1e-12f);

  float y[8] = {v0.x * inv, v0.y * inv, v0.z * inv, v0.w * inv,
                v1.x * inv, v1.y * inv, v1.z * inv, v1.w * inv};

  union { __hip_bfloat16 h[8]; uint4 u4; } pk;
  float sv = 0.f, rv = 0.f;
#pragma unroll
  for (int i = 0; i < 8; ++i) {
    pk.h[i] = __float2bfloat16(y[i]);
    sv += y[i] * y[i];
    rv += y[i];
  }
  ((uint4*)(Y + (size_t)rid * DIM))[lane] = pk.u4;

#pragma unroll
  for (int o = 1; o < 64; o <<= 1) {
    sv += __shfl_xor(sv, o, 64);
    rv += __shfl_xor(rv, o, 64);
  }
  if (lane == 0) {
    (is_low ? s_l : s_e)[row] = sv;
    (is_low ? r_l : r_e)[row] = rv;
  }
}

// ---------------------------------------------------------------------------
// Symmetric fused MFMA kernel, round 10: dl -> LDS f16 plane (kills the
// last register spill; R9 still wrote 39 MB scratch at the 128-reg cap).
// Register need now ~90 unified (acc 32 AGPR + frags 24 + addr/misc) under
// the (512,4) 128-cap -> 16 waves/CU, no spill.
// Grid: 561 blocks -> (br,bc) upper triangle, tile 128x128 (stride 127).
// 8 waves in 4x2 (wr=wid>>1 rows 32*wr.., wc=wid&1 cols 64*wc..),
// wave tile 32x64, ONE matrix at a time.
// Phase m=0 (low): K-loop -> distances -> f16 LDS plane dpl[129][130].
// Phase m=1 (emb): K-loop reusing acc -> de stays f32 in acc.
// K-loop: BK=64, 8 iters/phase, stage A(128 rows)+B(128 cols) = 32 KB via
//   global_load_lds w=16; K-chunk XOR-swizzled by row&7 on the GLOBAL side
//   (zero bank conflicts, verified R7-R9). Diagonal blocks skip B staging
//   and read B frags from the A segment.
// Epilogue: dl (and its j+1 / i+1 neighbors) from dpl; de via the R9-proven
//   register+shfl+hand path. C frag map (m89/m91): col=lane&15,
//   row=(lane>>4)*4+reg.
// ---------------------------------------------------------------------------
__global__ __launch_bounds__(512, 4) void fused_sym_kernel(
    const __hip_bfloat16* __restrict__ Y,
    const float* __restrict__ s_l, const float* __restrict__ r_l,
    const float* __restrict__ s_e, const float* __restrict__ r_e,
    float* __restrict__ out) {
  __shared__ __align__(16) __hip_bfloat16 lds[16384];  // 32 KB staging
  __shared__ _Float16 dpl[129 * 130];                  // dist_low plane, padded
  __shared__ float hand_d[4][32];    // de at tile col 64, per wr row-group
  __shared__ float hand_t[4][128];   // de at tile row 32*wr ([wr-1] slot)
  __shared__ float sred[8];

  // decode upper-triangle block id
  int rem = blockIdx.x, br = 0;
  while (rem >= NT - br) { rem -= NT - br; ++br; }
  const int bc = br + rem;
  const bool diag = (br == bc);

  const int tid = threadIdx.x;
  const int lane = tid & 63;
  const int wid = tid >> 6;          // 0..7
  const int wr = wid >> 1;           // 0..3: rows 32*wr..32*wr+31
  const int wc = wid & 1;            // 0..1: cols 64*wc..64*wc+63
  const int quad = lane >> 4, cpos = lane & 15;
  const int sw = cpos & 7;
  const int r0 = br * TSTRIDE, c0 = bc * TSTRIDE;

  // staging: 2048 slots of 16B; thread owns slot c = tid + 512*s, s=0..3.
  int goff[4];
#pragma unroll
  for (int s = 0; s < 4; ++s) {
    const int c = tid + 512 * s;
    int base;
    if (c < 1024) base = min(r0 + (c >> 3), BROWS - 1) * DIM;
    else          base = min(c0 + ((c - 1024) >> 3), BROWS - 1) * DIM;
    goff[s] = base + (((c & 7) ^ ((c >> 3) & 7)) << 3);
  }

  const int abase0 = (32 * wr + cpos) * 64;
  const int bbase0 = (diag ? 0 : 8192) + (64 * wc + cpos) * 64;

  const float epst = (float)DIM * 1e-6f * 1e-6f;
  f32x4 acc[2][4];

#pragma unroll
  for (int m = 0; m < 2; ++m) {
    const __hip_bfloat16* Ym = Y + m * YEMB_E;
#pragma unroll
    for (int u = 0; u < 2; ++u)
#pragma unroll
      for (int v = 0; v < 4; ++v) acc[u][v] = (f32x4)(0.f);

    for (int it = 0; it < 8; ++it) {
      const int k0 = it * 64;
#pragma unroll
      for (int s = 0; s < 4; ++s) {
        if (s < 2 || !diag)
          __builtin_amdgcn_global_load_lds(
              (const __attribute__((address_space(1))) void*)(Ym + goff[s] + k0),
              (__attribute__((address_space(3))) void*)(lds + (tid + 512 * s) * 8),
              16, 0, 0);
      }
      __syncthreads();

#pragma unroll
      for (int kk = 0; kk < 2; ++kk) {
        const int ch = ((kk * 4 + quad) ^ sw) << 3;
        bf16x8 a[2], b[4];
#pragma unroll
        for (int u = 0; u < 2; ++u)
          a[u] = *(const bf16x8*)&lds[abase0 + u * 1024 + ch];
#pragma unroll
        for (int v = 0; v < 4; ++v)
          b[v] = *(const bf16x8*)&lds[bbase0 + v * 1024 + ch];
#pragma unroll
        for (int u = 0; u < 2; ++u)
#pragma unroll
          for (int v = 0; v < 4; ++v)
            acc[u][v] = __builtin_amdgcn_mfma_f32_16x16x32_bf16(
                a[u], b[v], acc[u][v], 0, 0, 0);
      }
      __syncthreads();
    }

    // transform acc -> distances for this matrix
    const float* sp = m ? s_e : s_l;
    const float* rp = m ? r_e : r_l;
#pragma unroll
    for (int v = 0; v < 4; ++v) {
      const int tcol = 64 * wc + 16 * v + cpos;
      const int j = min(c0 + tcol, BROWS - 1);
      const float sj = sp[j], rj = rp[j];
#pragma unroll
      for (int u = 0; u < 2; ++u) {
#pragma unroll
        for (int r = 0; r < 4; ++r) {
          const int trow = 32 * wr + 16 * u + 4 * quad + r;
          const int i = min(r0 + trow, BROWS - 1);
          const float sq = sp[i] + sj - 2.f * acc[u][v][r] +
                           2e-6f * (rp[i] - rj) + epst;
          const float d = sqrtf(fmaxf(sq, 0.f));
          if (m == 0) dpl[trow * 130 + tcol] = (_Float16)d;
          else        acc[u][v][r] = d;
        }
      }
    }
  }
  // now: dl (f16) in dpl LDS plane, de (f32) in acc

  // ---- publish cross-wave de boundary values ----
  if (wc == 1 && cpos == 0) {   // tile col 64 for this wr's 32 rows
#pragma unroll
    for (int u = 0; u < 2; ++u)
#pragma unroll
      for (int r = 0; r < 4; ++r)
        hand_d[wr][16 * u + 4 * quad + r] = acc[u][0][r];
  }
  if (quad == 0 && wr >= 1) {   // tile row 32*wr (u=0,r=0) for 64 cols
#pragma unroll
    for (int v = 0; v < 4; ++v)
      hand_t[wr - 1][64 * wc + 16 * v + cpos] = acc[0][v][0];
  }
  __syncthreads();

  float sum = 0.f;

  // ---- pass 1: direct terms (i in rows, pair cols j,j+1) ----
  const int srcin = (lane & 48) | ((cpos + 1) & 15);
#pragma unroll
  for (int u = 0; u < 2; ++u)
#pragma unroll
    for (int r = 0; r < 4; ++r) {
      const int trow = 32 * wr + 16 * u + 4 * quad + r;
      const int i = r0 + trow;
      const bool rowok = (trow <= 126) && (i <= BROWS - 2);
#pragma unroll
      for (int v = 0; v < 4; ++v) {
        const int tcol = 64 * wc + 16 * v + cpos;
        const float de1 = acc[u][v][r];
        float de2 = __shfl(de1, srcin, 64);
        if (v < 3) {
          const float deb = __shfl(acc[u][v + 1][r], lane & 48, 64);
          if (cpos == 15) de2 = deb;
        } else if (cpos == 15 && wc == 0) {
          de2 = hand_d[wr][16 * u + 4 * quad + r];
        }
        const int j = c0 + tcol;
        if (rowok && tcol <= 126 && j <= BROWS - 3) {
          const float dl1 = (float)dpl[trow * 130 + tcol];
          const float dl2 = (float)dpl[trow * 130 + tcol + 1];
          const float aa = dl1 - dl2, bb = de1 - de2;
          const float coeff = (float)((aa > 0.f) - (aa < 0.f)) -
                              (float)((bb > 0.f) - (bb < 0.f));
          sum += coeff * (de2 - de1);
        }
      }
    }

  // ---- pass 2: transposed terms (i in cols, pair rows j,j+1), off-diag only ----
  if (!diag) {
#pragma unroll
    for (int u = 0; u < 2; ++u)
#pragma unroll
      for (int v = 0; v < 4; ++v) {
        const int tcol = 64 * wc + 16 * v + cpos;
        const int ii = c0 + tcol;
        const bool colok = (tcol <= 126) && (ii <= BROWS - 2);
#pragma unroll
        for (int r = 0; r < 4; ++r) {
          const int trow = 32 * wr + 16 * u + 4 * quad + r;
          const int jj = r0 + trow;
          float de2;
          if (r < 3) {
            de2 = acc[u][v][r + 1];
          } else {
            const float deq = __shfl(acc[u][v][0], (lane + 16) & 63, 64);
            const float deu = __shfl(acc[u ? u : 1][v][0], cpos, 64);
            if (quad < 3)    de2 = deq;
            else if (u == 0) de2 = deu;
            else             de2 = hand_t[wr][tcol];   // wr==3 filtered below
          }
          if (colok && trow <= 126 && jj <= BROWS - 3) {
            const float dl1 = (float)dpl[trow * 130 + tcol];
            const float dl2 = (float)dpl[(trow + 1) * 130 + tcol];
            const float de1 = acc[u][v][r];
            const float aa = dl1 - dl2, bb = de1 - de2;
            const float coeff = (float)((aa > 0.f) - (aa < 0.f)) -
                                (float)((bb > 0.f) - (bb < 0.f));
            sum += coeff * (de2 - de1);
          }
        }
      }
  }

  // ---- reduce + atomic ----
#pragma unroll
  for (int o = 32; o; o >>= 1) sum += __shfl_down(sum, o, 64);
  if (lane == 0) sred[wid] = sum;
  __syncthreads();
  if (tid == 0) {
    const float scale = 1.0f / ((float)(BROWS - 1) * (float)(BROWS - 2));
    float t = 0.f;
#pragma unroll
    for (int w = 0; w < 8; ++w) t += sred[w];
    atomicAdd(out, t * scale);
  }
}

// ===========================================================================
extern "C" void kernel_launch(void* const* d_in, const int* in_sizes, int n_in,
                              void* d_out, int out_size, void* d_ws,
                              size_t ws_size, hipStream_t stream) {
  const float* low = (const float*)d_in[0];
  const float* emb = (const float*)d_in[1];
  float* out = (float*)d_out;

  // ws: Y (2*4096*512 bf16 = 8 MB) then s_l, r_l, s_e, r_e (4096 f32 each)
  __hip_bfloat16* Y = (__hip_bfloat16*)d_ws;
  float* s_l = (float*)(Y + 2 * (size_t)BROWS * DIM);
  float* r_l = s_l + BROWS;
  float* s_e = r_l + BROWS;
  float* r_e = s_e + BROWS;

  prep3_kernel<<<2 * BROWS / 4, 256, 0, stream>>>(low, emb, Y, s_l, r_l, s_e, r_e, out);
  fused_sym_kernel<<<NT * (NT + 1) / 2, 512, 0, stream>>>(Y, s_l, r_l, s_e, r_e, out);
}

// Round 11
// 119.281 us; speedup vs baseline: 1.1755x; 1.1755x over previous
//
#include <hip/hip_runtime.h>
#include <hip/hip_bf16.h>
#include <math.h>

#define BROWS 4096
#define DIM   512
#define YEMB_E 2097152   // 4096*512, element offset of emb rows in Y
#define TSTRIDE 127      // tile stride (tiles are 128 wide, overlap by 1)
#define NT 33            // tiles per dim; triangle blocks = 33*34/2 = 561

typedef float f32x4 __attribute__((ext_vector_type(4)));
typedef __bf16 bf16x8 __attribute__((ext_vector_type(8)));

// ---------------------------------------------------------------------------
// prep3: wave-per-row, no barriers. 8192 rows (low then emb), 4 rows/block.
// ---------------------------------------------------------------------------
__global__ __launch_bounds__(256) void prep3_kernel(
    const float* __restrict__ low, const float* __restrict__ emb,
    __hip_bfloat16* __restrict__ Y,
    float* __restrict__ s_l, float* __restrict__ r_l,
    float* __restrict__ s_e, float* __restrict__ r_e,
    float* __restrict__ out) {
  const int tid = threadIdx.x;
  const int lane = tid & 63, wid = tid >> 6;
  const int rid = blockIdx.x * 4 + wid;          // 0..8191
  if (blockIdx.x == 0 && tid == 0) out[0] = 0.f;

  const bool is_low = (rid < BROWS);
  const int row = is_low ? rid : rid - BROWS;
  const float* x = (is_low ? low : emb) + (size_t)row * DIM;

  const float4 v0 = ((const float4*)x)[lane * 2];
  const float4 v1 = ((const float4*)x)[lane * 2 + 1];

  float ss = v0.x * v0.x + v0.y * v0.y + v0.z * v0.z + v0.w * v0.w +
             v1.x * v1.x + v1.y * v1.y + v1.z * v1.z + v1.w * v1.w;
#pragma unroll
  for (int o = 1; o < 64; o <<= 1) ss += __shfl_xor(ss, o, 64);
  const float inv = 1.0f / fmaxf(sqrtf(ss), 1e-12f);

  float y[8] = {v0.x * inv, v0.y * inv, v0.z * inv, v0.w * inv,
                v1.x * inv, v1.y * inv, v1.z * inv, v1.w * inv};

  union { __hip_bfloat16 h[8]; uint4 u4; } pk;
  float sv = 0.f, rv = 0.f;
#pragma unroll
  for (int i = 0; i < 8; ++i) {
    pk.h[i] = __float2bfloat16(y[i]);
    sv += y[i] * y[i];
    rv += y[i];
  }
  ((uint4*)(Y + (size_t)rid * DIM))[lane] = pk.u4;

#pragma unroll
  for (int o = 1; o < 64; o <<= 1) {
    sv += __shfl_xor(sv, o, 64);
    rv += __shfl_xor(rv, o, 64);
  }
  if (lane == 0) {
    (is_low ? s_l : s_e)[row] = sv;
    (is_low ? r_l : r_e)[row] = rv;
  }
}

// ---------------------------------------------------------------------------
// Symmetric fused MFMA kernel, round 11: BOTH matrices per K-round.
// R10 finding: barrier-latency-bound (spill-free == spilling == ~78 us;
// all pipes sum << observed). Cost ~ per-round vmcnt(0)+s_barrier drain x
// 16 rounds. R11 halves rounds: stage A_low+A_emb+B_low+B_emb (64 KB) per
// BK=64 round, 8 rounds total, both Gram accs live (64 AGPR).
// Grid: 561 blocks -> (br,bc) upper triangle, tile 128x128 (stride 127).
// 8 waves in 4x2 (wr rows 32*wr.., wc cols 64*wc..), wave tile 32x64.
// Staging XOR-swizzled by row&7 on the GLOBAL side (0 conflicts, R7-R10).
// Diagonal blocks skip B staging, read B frags from the A segments.
// Epilogue: accl->dl, acce->de in regs; pair terms via shfl + LDS hands
// (both dl and de channels). C frag map (m89/m91): col=lane&15,
// row=(lane>>4)*4+reg.
// ---------------------------------------------------------------------------
__global__ __launch_bounds__(512, 4) void fused_sym_kernel(
    const __hip_bfloat16* __restrict__ Y,
    const float* __restrict__ s_l, const float* __restrict__ r_l,
    const float* __restrict__ s_e, const float* __restrict__ r_e,
    float* __restrict__ out) {
  __shared__ __align__(16) __hip_bfloat16 lds[32768];  // 64 KB staging
  __shared__ float hand_d[4][32][2];    // dl/de at tile col 64, per wr
  __shared__ float hand_t[4][128][2];   // dl/de at tile row 32*wr ([wr-1])
  __shared__ float sred[8];

  // decode upper-triangle block id
  int rem = blockIdx.x, br = 0;
  while (rem >= NT - br) { rem -= NT - br; ++br; }
  const int bc = br + rem;
  const bool diag = (br == bc);

  const int tid = threadIdx.x;
  const int lane = tid & 63;
  const int wid = tid >> 6;          // 0..7
  const int wr = wid >> 1;           // 0..3: rows 32*wr..32*wr+31
  const int wc = wid & 1;            // 0..1: cols 64*wc..64*wc+63
  const int quad = lane >> 4, cpos = lane & 15;
  const int sw = cpos & 7;
  const int r0 = br * TSTRIDE, c0 = bc * TSTRIDE;

  // staging: 4096 slots of 16B; thread owns slot c = tid + 512*s, s=0..7.
  // segs (slots): [0,1024) A_low, [1024,2048) A_emb,
  //               [2048,3072) B_low, [3072,4096) B_emb.
  // stored K-chunk q holds global chunk q ^ (row&7).
  int goff[8];
#pragma unroll
  for (int s = 0; s < 8; ++s) {
    const int c = tid + 512 * s;
    int base;
    if (c < 1024)       base = min(r0 + (c >> 3), BROWS - 1) * DIM;
    else if (c < 2048)  base = YEMB_E + min(r0 + ((c - 1024) >> 3), BROWS - 1) * DIM;
    else if (c < 3072)  base = min(c0 + ((c - 2048) >> 3), BROWS - 1) * DIM;
    else                base = YEMB_E + min(c0 + ((c - 3072) >> 3), BROWS - 1) * DIM;
    goff[s] = base + (((c & 7) ^ ((c >> 3) & 7)) << 3);
  }

  // frag base offsets (elems; seg elem-offsets: Alow 0, Aemb 8192,
  // Blow 16384, Bemb 24576; row stride 64)
  const int abase_l = (32 * wr + cpos) * 64;            // + u*1024 + chunk
  const int abase_e = 8192 + (32 * wr + cpos) * 64;
  const int bbase_l = (diag ? 0 : 16384) + (64 * wc + cpos) * 64;   // + v*1024
  const int bbase_e = (diag ? 8192 : 24576) + (64 * wc + cpos) * 64;

  f32x4 accl[2][4], acce[2][4];
#pragma unroll
  for (int u = 0; u < 2; ++u)
#pragma unroll
    for (int v = 0; v < 4; ++v) {
      accl[u][v] = (f32x4)(0.f);
      acce[u][v] = (f32x4)(0.f);
    }

  for (int it = 0; it < 8; ++it) {
    const int k0 = it * 64;
#pragma unroll
    for (int s = 0; s < 8; ++s) {
      if (s < 4 || !diag)
        __builtin_amdgcn_global_load_lds(
            (const __attribute__((address_space(1))) void*)(Y + goff[s] + k0),
            (__attribute__((address_space(3))) void*)(lds + (tid + 512 * s) * 8),
            16, 0, 0);
    }
    __syncthreads();

#pragma unroll
    for (int kk = 0; kk < 2; ++kk) {
      const int ch = ((kk * 4 + quad) ^ sw) << 3;
      {  // low matrix
        bf16x8 a[2], b[4];
#pragma unroll
        for (int u = 0; u < 2; ++u) a[u] = *(const bf16x8*)&lds[abase_l + u * 1024 + ch];
#pragma unroll
        for (int v = 0; v < 4; ++v) b[v] = *(const bf16x8*)&lds[bbase_l + v * 1024 + ch];
#pragma unroll
        for (int u = 0; u < 2; ++u)
#pragma unroll
          for (int v = 0; v < 4; ++v)
            accl[u][v] = __builtin_amdgcn_mfma_f32_16x16x32_bf16(
                a[u], b[v], accl[u][v], 0, 0, 0);
      }
      {  // emb matrix
        bf16x8 a[2], b[4];
#pragma unroll
        for (int u = 0; u < 2; ++u) a[u] = *(const bf16x8*)&lds[abase_e + u * 1024 + ch];
#pragma unroll
        for (int v = 0; v < 4; ++v) b[v] = *(const bf16x8*)&lds[bbase_e + v * 1024 + ch];
#pragma unroll
        for (int u = 0; u < 2; ++u)
#pragma unroll
          for (int v = 0; v < 4; ++v)
            acce[u][v] = __builtin_amdgcn_mfma_f32_16x16x32_bf16(
                a[u], b[v], acce[u][v], 0, 0, 0);
      }
    }
    __syncthreads();
  }

  // ---- transform both accs -> distances in place ----
  const float epst = (float)DIM * 1e-6f * 1e-6f;
#pragma unroll
  for (int v = 0; v < 4; ++v) {
    const int j = min(c0 + 64 * wc + 16 * v + cpos, BROWS - 1);
    const float sjl = s_l[j], rjl = r_l[j];
    const float sje = s_e[j], rje = r_e[j];
#pragma unroll
    for (int u = 0; u < 2; ++u)
#pragma unroll
      for (int r = 0; r < 4; ++r) {
        const int i = min(r0 + 32 * wr + 16 * u + 4 * quad + r, BROWS - 1);
        const float sql = s_l[i] + sjl - 2.f * accl[u][v][r] +
                          2e-6f * (r_l[i] - rjl) + epst;
        accl[u][v][r] = sqrtf(fmaxf(sql, 0.f));
        const float sqe = s_e[i] + sje - 2.f * acce[u][v][r] +
                          2e-6f * (r_e[i] - rje) + epst;
        acce[u][v][r] = sqrtf(fmaxf(sqe, 0.f));
      }
  }
  // now: dl in accl, de in acce

  // ---- publish cross-wave boundary values (dl and de) ----
  if (wc == 1 && cpos == 0) {   // tile col 64 for this wr's 32 rows
#pragma unroll
    for (int u = 0; u < 2; ++u)
#pragma unroll
      for (int r = 0; r < 4; ++r) {
        hand_d[wr][16 * u + 4 * quad + r][0] = accl[u][0][r];
        hand_d[wr][16 * u + 4 * quad + r][1] = acce[u][0][r];
      }
  }
  if (quad == 0 && wr >= 1) {   // tile row 32*wr (u=0,r=0) for 64 cols
#pragma unroll
    for (int v = 0; v < 4; ++v) {
      hand_t[wr - 1][64 * wc + 16 * v + cpos][0] = accl[0][v][0];
      hand_t[wr - 1][64 * wc + 16 * v + cpos][1] = acce[0][v][0];
    }
  }
  __syncthreads();

  float sum = 0.f;

  // ---- pass 1: direct terms (i in rows, pair cols j,j+1) ----
  const int srcin = (lane & 48) | ((cpos + 1) & 15);
#pragma unroll
  for (int u = 0; u < 2; ++u)
#pragma unroll
    for (int r = 0; r < 4; ++r) {
      const int trow = 32 * wr + 16 * u + 4 * quad + r;
      const int i = r0 + trow;
      const bool rowok = (trow <= 126) && (i <= BROWS - 2);
#pragma unroll
      for (int v = 0; v < 4; ++v) {
        const float dl1 = accl[u][v][r], de1 = acce[u][v][r];
        float dl2 = __shfl(dl1, srcin, 64);
        float de2 = __shfl(de1, srcin, 64);
        if (v < 3) {
          const float dlb = __shfl(accl[u][v + 1][r], lane & 48, 64);
          const float deb = __shfl(acce[u][v + 1][r], lane & 48, 64);
          if (cpos == 15) { dl2 = dlb; de2 = deb; }
        } else if (cpos == 15 && wc == 0) {
          dl2 = hand_d[wr][16 * u + 4 * quad + r][0];
          de2 = hand_d[wr][16 * u + 4 * quad + r][1];
        }
        const int tcol = 64 * wc + 16 * v + cpos;
        const int j = c0 + tcol;
        if (rowok && tcol <= 126 && j <= BROWS - 3) {
          const float aa = dl1 - dl2, bb = de1 - de2;
          const float coeff = (float)((aa > 0.f) - (aa < 0.f)) -
                              (float)((bb > 0.f) - (bb < 0.f));
          sum += coeff * (de2 - de1);
        }
      }
    }

  // ---- pass 2: transposed terms (i in cols, pair rows j,j+1), off-diag only ----
  if (!diag) {
#pragma unroll
    for (int u = 0; u < 2; ++u)
#pragma unroll
      for (int v = 0; v < 4; ++v) {
        const int tcol = 64 * wc + 16 * v + cpos;
        const int ii = c0 + tcol;
        const bool colok = (tcol <= 126) && (ii <= BROWS - 2);
#pragma unroll
        for (int r = 0; r < 4; ++r) {
          const int trow = 32 * wr + 16 * u + 4 * quad + r;
          const int jj = r0 + trow;
          float dl2, de2;
          if (r < 3) {
            dl2 = accl[u][v][r + 1];
            de2 = acce[u][v][r + 1];
          } else {
            const float dlq = __shfl(accl[u][v][0], (lane + 16) & 63, 64);
            const float deq = __shfl(acce[u][v][0], (lane + 16) & 63, 64);
            const float dlu = __shfl(accl[1][v][0], cpos, 64);
            const float deu = __shfl(acce[1][v][0], cpos, 64);
            if (quad < 3)    { dl2 = dlq; de2 = deq; }
            else if (u == 0) { dl2 = dlu; de2 = deu; }
            else             { dl2 = hand_t[wr][tcol][0];   // wr==3 filtered
                               de2 = hand_t[wr][tcol][1]; }
          }
          if (colok && trow <= 126 && jj <= BROWS - 3) {
            const float dl1 = accl[u][v][r], de1 = acce[u][v][r];
            const float aa = dl1 - dl2, bb = de1 - de2;
            const float coeff = (float)((aa > 0.f) - (aa < 0.f)) -
                                (float)((bb > 0.f) - (bb < 0.f));
            sum += coeff * (de2 - de1);
          }
        }
      }
  }

  // ---- reduce + atomic ----
#pragma unroll
  for (int o = 32; o; o >>= 1) sum += __shfl_down(sum, o, 64);
  if (lane == 0) sred[wid] = sum;
  __syncthreads();
  if (tid == 0) {
    const float scale = 1.0f / ((float)(BROWS - 1) * (float)(BROWS - 2));
    float t = 0.f;
#pragma unroll
    for (int w = 0; w < 8; ++w) t += sred[w];
    atomicAdd(out, t * scale);
  }
}

// ===========================================================================
extern "C" void kernel_launch(void* const* d_in, const int* in_sizes, int n_in,
                              void* d_out, int out_size, void* d_ws,
                              size_t ws_size, hipStream_t stream) {
  const float* low = (const float*)d_in[0];
  const float* emb = (const float*)d_in[1];
  float* out = (float*)d_out;

  // ws: Y (2*4096*512 bf16 = 8 MB) then s_l, r_l, s_e, r_e (4096 f32 each)
  __hip_bfloat16* Y = (__hip_bfloat16*)d_ws;
  float* s_l = (float*)(Y + 2 * (size_t)BROWS * DIM);
  float* r_l = s_l + BROWS;
  float* s_e = r_l + BROWS;
  float* r_e = s_e + BROWS;

  prep3_kernel<<<2 * BROWS / 4, 256, 0, stream>>>(low, emb, Y, s_l, r_l, s_e, r_e, out);
  fused_sym_kernel<<<NT * (NT + 1) / 2, 512, 0, stream>>>(Y, s_l, r_l, s_e, r_e, out);
}

// Round 12
// 114.156 us; speedup vs baseline: 1.2283x; 1.0449x over previous
//
#include <hip/hip_runtime.h>
#include <hip/hip_bf16.h>
#include <hip/hip_fp8.h>
#include <math.h>

#define BROWS 4096
#define DIM   512
#define YEMB_B 2097152   // 4096*512 bytes, offset of emb rows in Yq (fp8)
#define TSTRIDE 127      // tile stride (tiles are 128 wide, overlap by 1)
#define NT 33            // tiles per dim; triangle blocks = 33*34/2 = 561

typedef float f32x4 __attribute__((ext_vector_type(4)));

// ---------------------------------------------------------------------------
// prep4: wave-per-row, no barriers. 8192 rows (low then emb), 4 rows/block.
// L2-normalize -> fp8 e4m3 row in Yq (row-major, 512 B/row);
// s=sum(y^2), r=sum(y) from f32 y (pre-quantization, matching reference).
// ---------------------------------------------------------------------------
__global__ __launch_bounds__(256) void prep4_kernel(
    const float* __restrict__ low, const float* __restrict__ emb,
    unsigned char* __restrict__ Yq,
    float* __restrict__ s_l, float* __restrict__ r_l,
    float* __restrict__ s_e, float* __restrict__ r_e,
    float* __restrict__ out) {
  const int tid = threadIdx.x;
  const int lane = tid & 63, wid = tid >> 6;
  const int rid = blockIdx.x * 4 + wid;          // 0..8191
  if (blockIdx.x == 0 && tid == 0) out[0] = 0.f;

  const bool is_low = (rid < BROWS);
  const int row = is_low ? rid : rid - BROWS;
  const float* x = (is_low ? low : emb) + (size_t)row * DIM;

  const float4 v0 = ((const float4*)x)[lane * 2];
  const float4 v1 = ((const float4*)x)[lane * 2 + 1];

  float ss = v0.x * v0.x + v0.y * v0.y + v0.z * v0.z + v0.w * v0.w +
             v1.x * v1.x + v1.y * v1.y + v1.z * v1.z + v1.w * v1.w;
#pragma unroll
  for (int o = 1; o < 64; o <<= 1) ss += __shfl_xor(ss, o, 64);
  const float inv = 1.0f / fmaxf(sqrtf(ss), 1e-12f);

  float y[8] = {v0.x * inv, v0.y * inv, v0.z * inv, v0.w * inv,
                v1.x * inv, v1.y * inv, v1.z * inv, v1.w * inv};

  union { unsigned char b[8]; unsigned long long u; } pk;
  float sv = 0.f, rv = 0.f;
#pragma unroll
  for (int i = 0; i < 8; ++i) {
    pk.b[i] = __hip_fp8_e4m3(y[i]).__x;   // OCP e4m3fn, HW RNE
    sv += y[i] * y[i];
    rv += y[i];
  }
  ((unsigned long long*)(Yq + (size_t)rid * 512))[lane] = pk.u;

#pragma unroll
  for (int o = 1; o < 64; o <<= 1) {
    sv += __shfl_xor(sv, o, 64);
    rv += __shfl_xor(rv, o, 64);
  }
  if (lane == 0) {
    (is_low ? s_l : s_e)[row] = sv;
    (is_low ? r_l : r_e)[row] = rv;
  }
}

// ---------------------------------------------------------------------------
// Symmetric fused MFMA kernel, round 12: fp8-e4m3 inputs + BK=128.
// R11 model (confirmed): time ~ rounds x (transfer + fixed latency/barrier).
// fp8 halves staged bytes (287->143 MB); BK=128 keeps 64 KB/round staging
// (same 4096-slot map + kc^(row&7) swizzle as R11) but rounds drop 8 -> 4.
// Grid: 561 blocks -> (br,bc) upper triangle, tile 128x128 (stride 127).
// 8 waves in 4x2 (wr rows 32*wr.., wc cols 64*wc..), wave tile 32x64,
// both matrices live (64 AGPR acc, no spill at the (512,4) 128-reg cap).
// MFMA: f32_16x16x32_fp8_fp8, i64 A/B operands (8 fp8/lane,
// A[m=lane&15][k=quad*8+j]); C/D layout shape-determined = bf16 case.
// Frag reads: ds_read_b64 at row*128 + ((2kk+(quad>>1))^(cpos&7))*16
// + (quad&1)*8 -> exactly 4 bank-accesses/bank = structural min.
// Diagonal blocks skip B staging, read B frags from the A segments.
// Epilogue: R11-proven shfl + LDS-hand pair-term paths (dl & de channels).
// ---------------------------------------------------------------------------
__global__ __launch_bounds__(512, 4) void fused_sym_kernel(
    const unsigned char* __restrict__ Yq,
    const float* __restrict__ s_l, const float* __restrict__ r_l,
    const float* __restrict__ s_e, const float* __restrict__ r_e,
    float* __restrict__ out) {
  __shared__ __align__(16) unsigned char lds8[65536];  // 64 KB staging
  __shared__ float hand_d[4][32][2];    // dl/de at tile col 64, per wr
  __shared__ float hand_t[4][128][2];   // dl/de at tile row 32*wr ([wr-1])
  __shared__ float sred[8];

  // decode upper-triangle block id
  int rem = blockIdx.x, br = 0;
  while (rem >= NT - br) { rem -= NT - br; ++br; }
  const int bc = br + rem;
  const bool diag = (br == bc);

  const int tid = threadIdx.x;
  const int lane = tid & 63;
  const int wid = tid >> 6;          // 0..7
  const int wr = wid >> 1;           // 0..3: rows 32*wr..32*wr+31
  const int wc = wid & 1;            // 0..1: cols 64*wc..64*wc+63
  const int quad = lane >> 4, cpos = lane & 15;
  const int sw = cpos & 7;
  const int r0 = br * TSTRIDE, c0 = bc * TSTRIDE;

  // staging: 4096 slots of 16B; thread owns slot c = tid + 512*s, s=0..7.
  // segs (slots): [0,1024) A_low, [1024,2048) A_emb,
  //               [2048,3072) B_low, [3072,4096) B_emb.  8 chunks/row.
  // stored K-chunk q holds global chunk q ^ (row&7)  [swizzle].
  int goff[8];   // BYTE offsets into Yq (add k0 per round)
#pragma unroll
  for (int s = 0; s < 8; ++s) {
    const int c = tid + 512 * s;
    int base;
    if (c < 1024)       base = min(r0 + (c >> 3), BROWS - 1) * 512;
    else if (c < 2048)  base = YEMB_B + min(r0 + ((c - 1024) >> 3), BROWS - 1) * 512;
    else if (c < 3072)  base = min(c0 + ((c - 2048) >> 3), BROWS - 1) * 512;
    else                base = YEMB_B + min(c0 + ((c - 3072) >> 3), BROWS - 1) * 512;
    goff[s] = base + (((c & 7) ^ ((c >> 3) & 7)) << 4);
  }

  // frag base byte offsets (seg offsets: Alow 0, Aemb 16384, Blow 32768,
  // Bemb 49152; row stride 128 B; u/v stride 16 rows = 2048 B)
  const int abase_l = (32 * wr + cpos) * 128;
  const int abase_e = 16384 + (32 * wr + cpos) * 128;
  const int bbase_l = (diag ? 0 : 32768) + (64 * wc + cpos) * 128;
  const int bbase_e = (diag ? 16384 : 49152) + (64 * wc + cpos) * 128;

  f32x4 accl[2][4], acce[2][4];
#pragma unroll
  for (int u = 0; u < 2; ++u)
#pragma unroll
    for (int v = 0; v < 4; ++v) {
      accl[u][v] = (f32x4)(0.f);
      acce[u][v] = (f32x4)(0.f);
    }

  for (int it = 0; it < 4; ++it) {
    const int k0 = it * 128;
#pragma unroll
    for (int s = 0; s < 8; ++s) {
      if (s < 4 || !diag)
        __builtin_amdgcn_global_load_lds(
            (const __attribute__((address_space(1))) void*)(Yq + goff[s] + k0),
            (__attribute__((address_space(3))) void*)(lds8 + (tid + 512 * s) * 16),
            16, 0, 0);
    }
    __syncthreads();

#pragma unroll
    for (int kk = 0; kk < 4; ++kk) {
      const int ch = (((2 * kk + (quad >> 1)) ^ sw) << 4) + (quad & 1) * 8;
      {  // low matrix
        long a[2], b[4];
#pragma unroll
        for (int u = 0; u < 2; ++u) a[u] = *(const long*)(lds8 + abase_l + u * 2048 + ch);
#pragma unroll
        for (int v = 0; v < 4; ++v) b[v] = *(const long*)(lds8 + bbase_l + v * 2048 + ch);
#pragma unroll
        for (int u = 0; u < 2; ++u)
#pragma unroll
          for (int v = 0; v < 4; ++v)
            accl[u][v] = __builtin_amdgcn_mfma_f32_16x16x32_fp8_fp8(
                a[u], b[v], accl[u][v], 0, 0, 0);
      }
      {  // emb matrix
        long a[2], b[4];
#pragma unroll
        for (int u = 0; u < 2; ++u) a[u] = *(const long*)(lds8 + abase_e + u * 2048 + ch);
#pragma unroll
        for (int v = 0; v < 4; ++v) b[v] = *(const long*)(lds8 + bbase_e + v * 2048 + ch);
#pragma unroll
        for (int u = 0; u < 2; ++u)
#pragma unroll
          for (int v = 0; v < 4; ++v)
            acce[u][v] = __builtin_amdgcn_mfma_f32_16x16x32_fp8_fp8(
                a[u], b[v], acce[u][v], 0, 0, 0);
      }
    }
    __syncthreads();
  }

  // ---- transform both accs -> distances in place ----
  const float epst = (float)DIM * 1e-6f * 1e-6f;
#pragma unroll
  for (int v = 0; v < 4; ++v) {
    const int j = min(c0 + 64 * wc + 16 * v + cpos, BROWS - 1);
    const float sjl = s_l[j], rjl = r_l[j];
    const float sje = s_e[j], rje = r_e[j];
#pragma unroll
    for (int u = 0; u < 2; ++u)
#pragma unroll
      for (int r = 0; r < 4; ++r) {
        const int i = min(r0 + 32 * wr + 16 * u + 4 * quad + r, BROWS - 1);
        const float sql = s_l[i] + sjl - 2.f * accl[u][v][r] +
                          2e-6f * (r_l[i] - rjl) + epst;
        accl[u][v][r] = sqrtf(fmaxf(sql, 0.f));
        const float sqe = s_e[i] + sje - 2.f * acce[u][v][r] +
                          2e-6f * (r_e[i] - rje) + epst;
        acce[u][v][r] = sqrtf(fmaxf(sqe, 0.f));
      }
  }
  // now: dl in accl, de in acce

  // ---- publish cross-wave boundary values (dl and de) ----
  if (wc == 1 && cpos == 0) {   // tile col 64 for this wr's 32 rows
#pragma unroll
    for (int u = 0; u < 2; ++u)
#pragma unroll
      for (int r = 0; r < 4; ++r) {
        hand_d[wr][16 * u + 4 * quad + r][0] = accl[u][0][r];
        hand_d[wr][16 * u + 4 * quad + r][1] = acce[u][0][r];
      }
  }
  if (quad == 0 && wr >= 1) {   // tile row 32*wr (u=0,r=0) for 64 cols
#pragma unroll
    for (int v = 0; v < 4; ++v) {
      hand_t[wr - 1][64 * wc + 16 * v + cpos][0] = accl[0][v][0];
      hand_t[wr - 1][64 * wc + 16 * v + cpos][1] = acce[0][v][0];
    }
  }
  __syncthreads();

  float sum = 0.f;

  // ---- pass 1: direct terms (i in rows, pair cols j,j+1) ----
  const int srcin = (lane & 48) | ((cpos + 1) & 15);
#pragma unroll
  for (int u = 0; u < 2; ++u)
#pragma unroll
    for (int r = 0; r < 4; ++r) {
      const int trow = 32 * wr + 16 * u + 4 * quad + r;
      const int i = r0 + trow;
      const bool rowok = (trow <= 126) && (i <= BROWS - 2);
#pragma unroll
      for (int v = 0; v < 4; ++v) {
        const float dl1 = accl[u][v][r], de1 = acce[u][v][r];
        float dl2 = __shfl(dl1, srcin, 64);
        float de2 = __shfl(de1, srcin, 64);
        if (v < 3) {
          const float dlb = __shfl(accl[u][v + 1][r], lane & 48, 64);
          const float deb = __shfl(acce[u][v + 1][r], lane & 48, 64);
          if (cpos == 15) { dl2 = dlb; de2 = deb; }
        } else if (cpos == 15 && wc == 0) {
          dl2 = hand_d[wr][16 * u + 4 * quad + r][0];
          de2 = hand_d[wr][16 * u + 4 * quad + r][1];
        }
        const int tcol = 64 * wc + 16 * v + cpos;
        const int j = c0 + tcol;
        if (rowok && tcol <= 126 && j <= BROWS - 3) {
          const float aa = dl1 - dl2, bb = de1 - de2;
          const float coeff = (float)((aa > 0.f) - (aa < 0.f)) -
                              (float)((bb > 0.f) - (bb < 0.f));
          sum += coeff * (de2 - de1);
        }
      }
    }

  // ---- pass 2: transposed terms (i in cols, pair rows j,j+1), off-diag only ----
  if (!diag) {
#pragma unroll
    for (int u = 0; u < 2; ++u)
#pragma unroll
      for (int v = 0; v < 4; ++v) {
        const int tcol = 64 * wc + 16 * v + cpos;
        const int ii = c0 + tcol;
        const bool colok = (tcol <= 126) && (ii <= BROWS - 2);
#pragma unroll
        for (int r = 0; r < 4; ++r) {
          const int trow = 32 * wr + 16 * u + 4 * quad + r;
          const int jj = r0 + trow;
          float dl2, de2;
          if (r < 3) {
            dl2 = accl[u][v][r + 1];
            de2 = acce[u][v][r + 1];
          } else {
            const float dlq = __shfl(accl[u][v][0], (lane + 16) & 63, 64);
            const float deq = __shfl(acce[u][v][0], (lane + 16) & 63, 64);
            const float dlu = __shfl(accl[1][v][0], cpos, 64);
            const float deu = __shfl(acce[1][v][0], cpos, 64);
            if (quad < 3)    { dl2 = dlq; de2 = deq; }
            else if (u == 0) { dl2 = dlu; de2 = deu; }
            else             { dl2 = hand_t[wr][tcol][0];   // wr==3 filtered
                               de2 = hand_t[wr][tcol][1]; }
          }
          if (colok && trow <= 126 && jj <= BROWS - 3) {
            const float dl1 = accl[u][v][r], de1 = acce[u][v][r];
            const float aa = dl1 - dl2, bb = de1 - de2;
            const float coeff = (float)((aa > 0.f) - (aa < 0.f)) -
                                (float)((bb > 0.f) - (bb < 0.f));
            sum += coeff * (de2 - de1);
          }
        }
      }
  }

  // ---- reduce + atomic ----
#pragma unroll
  for (int o = 32; o; o >>= 1) sum += __shfl_down(sum, o, 64);
  if (lane == 0) sred[wid] = sum;
  __syncthreads();
  if (tid == 0) {
    const float scale = 1.0f / ((float)(BROWS - 1) * (float)(BROWS - 2));
    float t = 0.f;
#pragma unroll
    for (int w = 0; w < 8; ++w) t += sred[w];
    atomicAdd(out, t * scale);
  }
}

// ===========================================================================
extern "C" void kernel_launch(void* const* d_in, const int* in_sizes, int n_in,
                              void* d_out, int out_size, void* d_ws,
                              size_t ws_size, hipStream_t stream) {
  const float* low = (const float*)d_in[0];
  const float* emb = (const float*)d_in[1];
  float* out = (float*)d_out;

  // ws: Yq (2*4096*512 fp8 = 4 MB) then s_l, r_l, s_e, r_e (4096 f32 each)
  unsigned char* Yq = (unsigned char*)d_ws;
  float* s_l = (float*)(Yq + 2 * (size_t)BROWS * DIM);
  float* r_l = s_l + BROWS;
  float* s_e = r_l + BROWS;
  float* r_e = s_e + BROWS;

  prep4_kernel<<<2 * BROWS / 4, 256, 0, stream>>>(low, emb, Yq, s_l, r_l, s_e, r_e, out);
  fused_sym_kernel<<<NT * (NT + 1) / 2, 512, 0, stream>>>(Yq, s_l, r_l, s_e, r_e, out);
}